// Round 9
// baseline (4206.533 us; speedup 1.0000x reference)
//
#include <hip/hip_runtime.h>
#include <math.h>

#define NCH   14595
#define WROW  14600          // row stride (floats) in transposed workspace
#define HR_C  13
#define IMG_H 512
#define IMG_W 512
#define BS    4

typedef float f32x4 __attribute__((ext_vector_type(4)));

// param layout per lr-pixel row: [bias|W] per layer, starts:
// L0:0 (1920), L1:1920 (4160), L2:6080 (4160), L3:10240 (4160), L4:14400 (195)

__global__ __launch_bounds__(256) void transpose_params(const float* __restrict__ lp,
                                                        float* __restrict__ wsT) {
    __shared__ float tile[64][65];
    int bid = blockIdx.x;
    int pt = bid & 15;
    int t  = bid >> 4;
    int ct = t % 229;
    int b  = t / 229;
    int c0 = ct * 64, p0 = pt * 64;
    int tp = threadIdx.x & 63;
    int tr = threadIdx.x >> 6;
#pragma unroll
    for (int s = 0; s < 16; s++) {
        int c = c0 + tr + s * 4;
        if (c < NCH)
            tile[tr + s * 4][tp] = lp[((size_t)b * NCH + c) * 1024 + p0 + tp];
    }
    __syncthreads();
#pragma unroll
    for (int s = 0; s < 16; s++) {
        int p = p0 + tr + s * 4;
        int c = c0 + tp;
        if (c < NCH)
            wsT[((size_t)b * 1024 + p) * WROW + c] = tile[tp][tr + s * 4];
    }
}

// LDS-only barrier: never drains vmcnt.
__device__ __forceinline__ void block_sync_lds() {
    __builtin_amdgcn_sched_barrier(0);
    asm volatile("s_waitcnt lgkmcnt(0)" ::: "memory");
    __builtin_amdgcn_s_barrier();
    __builtin_amdgcn_sched_barrier(0);
}

// Load one weight bank: 4 k-steps x 8 ch (vmcnt queue, in-order, counted).
__device__ __forceinline__ void load_group(f32x4 (&w)[8], const float* wk, int kb) {
#pragma unroll
    for (int kk = 0; kk < 4; kk++) {
        w[2 * kk]     = *(const f32x4*)(wk + ((kb + kk) << 6));
        w[2 * kk + 1] = *(const f32x4*)(wk + ((kb + kk) << 6) + 4);
    }
}

// Consume one bank: 4 k-steps, acts via ds_read_b128 (lgkm, DS-only queue).
__device__ __forceinline__ void fma_group(const float* __restrict__ ap, int kb,
                                          const f32x4 (&w)[8], float acc[4][8]) {
#pragma unroll
    for (int kk = 0; kk < 4; kk++) {
        f32x4 a  = *(const f32x4*)(ap + ((kb + kk) << 8));
        f32x4 w0 = w[2 * kk], w1 = w[2 * kk + 1];
#pragma unroll
        for (int i = 0; i < 4; i++) {
            float av = a[i];
            acc[i][0] = fmaf(av, w0.x, acc[i][0]);
            acc[i][1] = fmaf(av, w0.y, acc[i][1]);
            acc[i][2] = fmaf(av, w0.z, acc[i][2]);
            acc[i][3] = fmaf(av, w0.w, acc[i][3]);
            acc[i][4] = fmaf(av, w1.x, acc[i][4]);
            acc[i][5] = fmaf(av, w1.y, acc[i][5]);
            acc[i][6] = fmaf(av, w1.z, acc[i][6]);
            acc[i][7] = fmaf(av, w1.w, acc[i][7]);
        }
    }
}

// Hidden layer, NG groups of 4 k-steps, double-buffered weight banks.
template<int NG>
__device__ __forceinline__ void layer_ws(const float* __restrict__ actT,
                                         const float* __restrict__ wop,
                                         int lstart, int o0, int px0,
                                         float acc[4][8]) {
    f32x4 b0 = *(const f32x4*)(wop + lstart + o0);
    f32x4 b1 = *(const f32x4*)(wop + lstart + o0 + 4);
#pragma unroll
    for (int i = 0; i < 4; i++)
#pragma unroll
        for (int j = 0; j < 4; j++) {
            acc[i][j] = b0[j];
            acc[i][4 + j] = b1[j];
        }
    const float* wk = wop + lstart + 64 + o0;
    const float* ap = actT + px0;
    f32x4 wA[8], wB[8];
    load_group(wA, wk, 0);
    load_group(wB, wk, 4);
#pragma unroll 1
    for (int g = 0; g < NG - 2; g += 2) {
        fma_group(ap, (g) * 4, wA, acc);
        load_group(wA, wk, (g + 2) * 4);
        fma_group(ap, (g + 1) * 4, wB, acc);
        load_group(wB, wk, (g + 3) * 4);
    }
    fma_group(ap, (NG - 2) * 4, wA, acc);
    fma_group(ap, (NG - 1) * 4, wB, acc);
}

// --------- slow fallback (no workspace) ----------
template<int NCI>
__device__ __forceinline__ void mlp_layer_slow(const float* __restrict__ actT,
                                               const float* __restrict__ lp_col,
                                               int loff, int o0,
                                               int px0, float acc[4][8]) {
#pragma unroll
    for (int j = 0; j < 8; j++) {
        float bv = lp_col[(size_t)(loff + o0 + j) << 10];
        acc[0][j] = bv; acc[1][j] = bv; acc[2][j] = bv; acc[3][j] = bv;
    }
#pragma unroll 2
    for (int k = 0; k < NCI; k++) {
        f32x4 a = *(const f32x4*)&actT[k * 256 + px0];
#pragma unroll
        for (int j = 0; j < 8; j++) {
            float w = lp_col[(size_t)(loff + 64 + (k << 6) + o0 + j) << 10];
#pragma unroll
            for (int i = 0; i < 4; i++)
                acc[i][j] = fmaf(a[i], w, acc[i][j]);
        }
    }
}

template<bool USE_WS>
__global__ __launch_bounds__(512)
__attribute__((amdgpu_waves_per_eu(4, 4)))   // pin EXACTLY 4 waves/SIMD -> 128 VGPR budget, no spill
void asap_main(const float* __restrict__ hr,
               const float* __restrict__ lp,
               const float* __restrict__ wsT,
               float* __restrict__ out) {
    __shared__ __align__(16) float actT[64 * 256];   // [ch][px] full 16x16 tile, 64 KB

    // XCD-chunked swizzle (4096 blocks, 512 per XCD, bijective)
    int bid0 = blockIdx.x;
    int bid  = ((bid0 & 7) << 9) | (bid0 >> 3);

    int x   = bid & 31;
    int y   = (bid >> 5) & 31;
    int b   = bid >> 10;
    int tid = threadIdx.x;
    int lane = tid & 63;
    int wv   = tid >> 6;                 // 0..7
    int pix  = y * 32 + x;

    const float* wrow   = wsT + ((size_t)b * 1024 + pix) * WROW;
    const float* lp_col = lp + (size_t)b * NCH * 1024 + pix;

    // Opacify: forces VGPR pointer -> weight loads are global_load_dwordx4 on
    // the in-order vmcnt queue (counted waits), not s_load on lgkmcnt.
    const float* wop = wrow;
    asm("" : "+v"(wop));

    // ---- build inputs: hr channels + cosine coords; zero pad rows 29..31 ----
    {
        int Y0 = y * 16, X0 = x * 16;
        for (int t = tid; t < HR_C * 256; t += 512) {
            int c = t >> 8, p = t & 255;
            actT[c * 256 + p] =
                hr[(((size_t)b * HR_C + c) * IMG_H + Y0 + (p >> 4)) * IMG_W + X0 + (p & 15)];
        }
        if (tid < 256) {
            int p = tid, kx = p & 15, ky = p >> 4;
            const float two_pi = 6.28318530717958647692f;
            int f = 16;
#pragma unroll
            for (int fi = 0; fi < 4; fi++) {
                float ax = two_pi * (float)(kx & (f - 1)) / (float)f;
                float ay = two_pi * (float)(ky & (f - 1)) / (float)f;
                actT[(13 + 4 * fi + 0) * 256 + p] = cosf(ax);
                actT[(13 + 4 * fi + 1) * 256 + p] = sinf(ax);
                actT[(13 + 4 * fi + 2) * 256 + p] = cosf(ay);
                actT[(13 + 4 * fi + 3) * 256 + p] = sinf(ay);
                f >>= 1;
            }
            actT[29 * 256 + p] = 0.f;
            actT[30 * 256 + p] = 0.f;
            actT[31 * 256 + p] = 0.f;
        }
    }
    block_sync_lds();

    int o0  = wv << 3;                   // 8 out-ch per wave
    int px0 = lane << 2;                 // 4 px per lane
    float acc[4][8];

    auto writeback = [&]() {
#pragma unroll
        for (int j = 0; j < 8; j++) {
            f32x4 v;
            v.x = acc[0][j]; v.y = acc[1][j]; v.z = acc[2][j]; v.w = acc[3][j];
            v.x = fmaxf(v.x, 0.01f * v.x);
            v.y = fmaxf(v.y, 0.01f * v.y);
            v.z = fmaxf(v.z, 0.01f * v.z);
            v.w = fmaxf(v.w, 0.01f * v.w);
            *(f32x4*)&actT[(o0 + j) * 256 + px0] = v;
        }
    };

    if (USE_WS) {
        layer_ws<8>(actT, wop, 0, o0, px0, acc);      // L0: nci 29 padded to 32
        block_sync_lds(); writeback(); block_sync_lds();
        layer_ws<16>(actT, wop, 1920, o0, px0, acc);
        block_sync_lds(); writeback(); block_sync_lds();
        layer_ws<16>(actT, wop, 6080, o0, px0, acc);
        block_sync_lds(); writeback(); block_sync_lds();
        layer_ws<16>(actT, wop, 10240, o0, px0, acc);
        block_sync_lds(); writeback(); block_sync_lds();

        // ---- final layer: nci=64, nco=3, tanh; threads 0..255 own a pixel ----
        if (tid < 256) {
            int p = tid;
            float s0 = wop[14400], s1 = wop[14401], s2 = wop[14402];
#pragma unroll 8
            for (int k = 0; k < 64; k++) {
                float a = actT[k * 256 + p];
                s0 = fmaf(a, wop[14403 + k * 3 + 0], s0);
                s1 = fmaf(a, wop[14403 + k * 3 + 1], s1);
                s2 = fmaf(a, wop[14403 + k * 3 + 2], s2);
            }
            int Y = y * 16 + (p >> 4), X = x * 16 + (p & 15);
            size_t base = ((size_t)b * 3) * IMG_H * IMG_W + (size_t)Y * IMG_W + X;
            out[base]                             = tanhf(s0);
            out[base + (size_t)IMG_H * IMG_W]     = tanhf(s1);
            out[base + (size_t)2 * IMG_H * IMG_W] = tanhf(s2);
        }
    } else {
        mlp_layer_slow<29>(actT, lp_col, 0,     o0, px0, acc);
        block_sync_lds(); writeback(); block_sync_lds();
        mlp_layer_slow<64>(actT, lp_col, 1920,  o0, px0, acc);
        block_sync_lds(); writeback(); block_sync_lds();
        mlp_layer_slow<64>(actT, lp_col, 6080,  o0, px0, acc);
        block_sync_lds(); writeback(); block_sync_lds();
        mlp_layer_slow<64>(actT, lp_col, 10240, o0, px0, acc);
        block_sync_lds(); writeback(); block_sync_lds();
        if (tid < 256) {
            int p = tid;
            float s0 = lp_col[(size_t)14400 << 10];
            float s1 = lp_col[(size_t)14401 << 10];
            float s2 = lp_col[(size_t)14402 << 10];
#pragma unroll 4
            for (int k = 0; k < 64; k++) {
                float a = actT[k * 256 + p];
                s0 = fmaf(a, lp_col[(size_t)(14403 + k * 3 + 0) << 10], s0);
                s1 = fmaf(a, lp_col[(size_t)(14403 + k * 3 + 1) << 10], s1);
                s2 = fmaf(a, lp_col[(size_t)(14403 + k * 3 + 2) << 10], s2);
            }
            int Y = y * 16 + (p >> 4), X = x * 16 + (p & 15);
            size_t base = ((size_t)b * 3) * IMG_H * IMG_W + (size_t)Y * IMG_W + X;
            out[base]                             = tanhf(s0);
            out[base + (size_t)IMG_H * IMG_W]     = tanhf(s1);
            out[base + (size_t)2 * IMG_H * IMG_W] = tanhf(s2);
        }
    }
}

extern "C" void kernel_launch(void* const* d_in, const int* in_sizes, int n_in,
                              void* d_out, int out_size, void* d_ws, size_t ws_size,
                              hipStream_t stream) {
    const float* hr = (const float*)d_in[0];
    const float* lp = (const float*)d_in[1];
    float* out = (float*)d_out;
    float* wsT = (float*)d_ws;

    size_t need = (size_t)BS * 1024 * WROW * sizeof(float);
    if (ws_size >= need) {
        transpose_params<<<BS * 229 * 16, 256, 0, stream>>>(lp, wsT);
        asap_main<true><<<4096, 512, 0, stream>>>(hr, lp, wsT, out);
    } else {
        asap_main<false><<<4096, 512, 0, stream>>>(hr, lp, wsT, out);
    }
}

// Round 10
// 564.955 us; speedup vs baseline: 7.4458x; 7.4458x over previous
//
#include <hip/hip_runtime.h>
#include <math.h>

#define NCH   14595
#define WROW  14600          // row stride (floats) in transposed workspace
#define HR_C  13
#define IMG_H 512
#define IMG_W 512
#define BS    4

typedef float f32x4 __attribute__((ext_vector_type(4)));

// param layout per lr-pixel row: [bias|W] per layer, starts:
// L0:0 (1920), L1:1920 (4160), L2:6080 (4160), L3:10240 (4160), L4:14400 (195)

__global__ __launch_bounds__(256) void transpose_params(const float* __restrict__ lp,
                                                        float* __restrict__ wsT) {
    __shared__ float tile[64][65];
    int bid = blockIdx.x;
    int pt = bid & 15;
    int t  = bid >> 4;
    int ct = t % 229;
    int b  = t / 229;
    int c0 = ct * 64, p0 = pt * 64;
    int tp = threadIdx.x & 63;
    int tr = threadIdx.x >> 6;
#pragma unroll
    for (int s = 0; s < 16; s++) {
        int c = c0 + tr + s * 4;
        if (c < NCH)
            tile[tr + s * 4][tp] = lp[((size_t)b * NCH + c) * 1024 + p0 + tp];
    }
    __syncthreads();
#pragma unroll
    for (int s = 0; s < 16; s++) {
        int p = p0 + tr + s * 4;
        int c = c0 + tp;
        if (c < NCH)
            wsT[((size_t)b * 1024 + p) * WROW + c] = tile[tp][tr + s * 4];
    }
}

// LDS-only barrier: orders DS ops, never drains vmcnt (weight chunk stays in flight).
__device__ __forceinline__ void block_sync_lds() {
    __builtin_amdgcn_sched_barrier(0);
    asm volatile("s_waitcnt lgkmcnt(0)" ::: "memory");
    __builtin_amdgcn_s_barrier();
    __builtin_amdgcn_sched_barrier(0);
}

__device__ __forceinline__ void wait_vm0() {
    asm volatile("s_waitcnt vmcnt(0)" ::: "memory");
    __builtin_amdgcn_sched_barrier(0);
}

// Stage one 4KB weight chunk (1024 floats) global->LDS on the vmcnt queue.
// One global_load_lds_dwordx4 per wave; LDS dest is wave-uniform base + lane*16.
__device__ __forceinline__ void issue_chunk(const float* __restrict__ wsrow, int gbase,
                                            float* ldsdst, int tid) {
    int idx = gbase + (tid << 2);
    idx = idx > (WROW - 4) ? (WROW - 4) : idx;   // clamp L4 tail in-bounds (extra slots unused)
    const float* gp = wsrow + idx;
    float* lp = ldsdst + ((tid >> 6) << 8);      // wave wv covers floats [wv*256, wv*256+256)
    __builtin_amdgcn_global_load_lds(
        (const __attribute__((address_space(1))) unsigned int*)gp,
        (__attribute__((address_space(3))) unsigned int*)lp,
        16, 0, 0);
}

// One hidden layer: NC chunks of 16 k. Lane = 8 px x 8 ch.
template<int NC>
__device__ __forceinline__ void layer_ws(const float* __restrict__ actT,
                                         float (*__restrict__ wbuf)[1024], int& buf,
                                         const float* __restrict__ wsrow,
                                         const float* __restrict__ wop,
                                         int lstart, int nextbase,
                                         int tid, int j0, int px0,
                                         float (&acc)[8][8]) {
    // biases (global vector loads, drained by the g=0 wait)
    f32x4 b0 = *(const f32x4*)(wop + lstart + j0);
    f32x4 b1 = *(const f32x4*)(wop + lstart + j0 + 4);
#pragma unroll
    for (int p = 0; p < 8; p++)
#pragma unroll
        for (int q = 0; q < 4; q++) {
            acc[p][q] = b0[q];
            acc[p][q + 4] = b1[q];
        }
#pragma unroll 1
    for (int g = 0; g < NC; g++) {
        wait_vm0();                      // chunk g (my wave's quarter) landed
        block_sync_lds();                // all quarters landed; prior reads done
        int nb = (g == NC - 1) ? nextbase : (lstart + 64 + (g + 1) * 1024);
        issue_chunk(wsrow, nb, &wbuf[buf ^ 1][0], tid);
        const float* wc = &wbuf[buf][0];
        const float* ab = actT + (g << 4) * 256 + px0;
#pragma unroll 4
        for (int kk = 0; kk < 16; kk++) {
            f32x4 a0 = *(const f32x4*)(ab + kk * 256);
            f32x4 a1 = *(const f32x4*)(ab + kk * 256 + 4);
            f32x4 w0 = *(const f32x4*)(wc + (kk << 6) + j0);
            f32x4 w1 = *(const f32x4*)(wc + (kk << 6) + j0 + 4);
#pragma unroll
            for (int p = 0; p < 4; p++)
#pragma unroll
                for (int q = 0; q < 4; q++) {
                    acc[p][q]         = fmaf(a0[p], w0[q], acc[p][q]);
                    acc[p][q + 4]     = fmaf(a0[p], w1[q], acc[p][q + 4]);
                    acc[p + 4][q]     = fmaf(a1[p], w0[q], acc[p + 4][q]);
                    acc[p + 4][q + 4] = fmaf(a1[p], w1[q], acc[p + 4][q + 4]);
                }
        }
        buf ^= 1;
    }
}

// --------- slow fallback (no workspace) ----------
template<int NCI>
__device__ __forceinline__ void mlp_layer_slow(const float* __restrict__ actT,
                                               const float* __restrict__ lp_col,
                                               int loff, int j0, int px0,
                                               float (&acc)[8][8]) {
#pragma unroll
    for (int j = 0; j < 8; j++) {
        float bv = lp_col[(size_t)(loff + j0 + j) << 10];
#pragma unroll
        for (int p = 0; p < 8; p++) acc[p][j] = bv;
    }
#pragma unroll 2
    for (int k = 0; k < NCI; k++) {
        f32x4 a0 = *(const f32x4*)&actT[k * 256 + px0];
        f32x4 a1 = *(const f32x4*)&actT[k * 256 + px0 + 4];
#pragma unroll
        for (int j = 0; j < 8; j++) {
            float w = lp_col[(size_t)(loff + 64 + (k << 6) + j0 + j) << 10];
#pragma unroll
            for (int p = 0; p < 4; p++) {
                acc[p][j]     = fmaf(a0[p], w, acc[p][j]);
                acc[p + 4][j] = fmaf(a1[p], w, acc[p + 4][j]);
            }
        }
    }
}

template<bool USE_WS>
__global__ __launch_bounds__(256, 2) void asap_main(const float* __restrict__ hr,
                                                    const float* __restrict__ lp,
                                                    const float* __restrict__ wsT,
                                                    float* __restrict__ out) {
    __shared__ __align__(16) float actT[64 * 256];   // [ch][px] 16x16 tile, 64 KB
    __shared__ __align__(16) float wbuf[2][1024];    // weight chunk double-buffer, 8 KB

    // XCD-chunked swizzle (4096 blocks, 512 per XCD, bijective)
    int bid0 = blockIdx.x;
    int bid  = ((bid0 & 7) << 9) | (bid0 >> 3);

    int x   = bid & 31;
    int y   = (bid >> 5) & 31;
    int b   = bid >> 10;
    int tid = threadIdx.x;
    int pix = y * 32 + x;

    const float* wsrow  = wsT + ((size_t)b * 1024 + pix) * WROW;
    const float* lp_col = lp + (size_t)b * NCH * 1024 + pix;
    const float* wop = wsrow;
    asm("" : "+v"(wop));                 // bias loads -> VMEM vector loads (vmcnt)

    int buf = 0;
    if (USE_WS) issue_chunk(wsrow, 64, &wbuf[0][0], tid);   // L0 chunk0, earliest

    // ---- build inputs: hr channels + cosine coords; zero pad rows 29..31 ----
    {
        int Y0 = y * 16, X0 = x * 16;
        for (int t = tid; t < HR_C * 256; t += 256) {
            int c = t >> 8, p = t & 255;
            actT[c * 256 + p] =
                hr[(((size_t)b * HR_C + c) * IMG_H + Y0 + (p >> 4)) * IMG_W + X0 + (p & 15)];
        }
        {
            int p = tid, kx = p & 15, ky = p >> 4;
            const float two_pi = 6.28318530717958647692f;
            int f = 16;
#pragma unroll
            for (int fi = 0; fi < 4; fi++) {
                float ax = two_pi * (float)(kx & (f - 1)) / (float)f;
                float ay = two_pi * (float)(ky & (f - 1)) / (float)f;
                actT[(13 + 4 * fi + 0) * 256 + p] = cosf(ax);
                actT[(13 + 4 * fi + 1) * 256 + p] = sinf(ax);
                actT[(13 + 4 * fi + 2) * 256 + p] = cosf(ay);
                actT[(13 + 4 * fi + 3) * 256 + p] = sinf(ay);
                f >>= 1;
            }
            actT[29 * 256 + p] = 0.f;
            actT[30 * 256 + p] = 0.f;
            actT[31 * 256 + p] = 0.f;
        }
    }

    int pg = tid & 31, oc = tid >> 5;    // 32 px-groups x 8 ch-octets
    int px0 = pg << 3;                   // 8 px per lane
    int j0  = oc << 3;                   // 8 ch per lane
    float acc[8][8];

    auto writeback = [&]() {
        block_sync_lds();                // all waves done reading this layer's acts
#pragma unroll
        for (int j = 0; j < 8; j++) {
            f32x4 v0, v1;
#pragma unroll
            for (int p = 0; p < 4; p++) {
                float u0 = acc[p][j], u1 = acc[p + 4][j];
                v0[p] = fmaxf(u0, 0.01f * u0);
                v1[p] = fmaxf(u1, 0.01f * u1);
            }
            *(f32x4*)&actT[(j0 + j) * 256 + px0] = v0;
            *(f32x4*)&actT[(j0 + j) * 256 + px0 + 4] = v1;
        }
    };

    if (USE_WS) {
        layer_ws<2>(actT, wbuf, buf, wsrow, wop, 0,     1984,  tid, j0, px0, acc);
        writeback();
        layer_ws<4>(actT, wbuf, buf, wsrow, wop, 1920,  6144,  tid, j0, px0, acc);
        writeback();
        layer_ws<4>(actT, wbuf, buf, wsrow, wop, 6080,  10304, tid, j0, px0, acc);
        writeback();
        layer_ws<4>(actT, wbuf, buf, wsrow, wop, 10240, 14400, tid, j0, px0, acc);
        writeback();

        // ---- final layer: nci=64, nco=3, tanh; thread = pixel ----
        wait_vm0();                      // L4 chunk landed
        block_sync_lds();                // visible + L3 writeback visible
        const float* wf = &wbuf[buf][0]; // [bias(3) | W(64x3)]
        int p = tid;
        float s0 = wf[0], s1 = wf[1], s2 = wf[2];
#pragma unroll 8
        for (int k = 0; k < 64; k++) {
            float a = actT[k * 256 + p];
            s0 = fmaf(a, wf[3 + k * 3 + 0], s0);
            s1 = fmaf(a, wf[3 + k * 3 + 1], s1);
            s2 = fmaf(a, wf[3 + k * 3 + 2], s2);
        }
        int Y = y * 16 + (p >> 4), X = x * 16 + (p & 15);
        size_t base = ((size_t)b * 3) * IMG_H * IMG_W + (size_t)Y * IMG_W + X;
        out[base]                             = tanhf(s0);
        out[base + (size_t)IMG_H * IMG_W]     = tanhf(s1);
        out[base + (size_t)2 * IMG_H * IMG_W] = tanhf(s2);
    } else {
        block_sync_lds();
        mlp_layer_slow<29>(actT, lp_col, 0,     j0, px0, acc);
        writeback(); block_sync_lds();
        mlp_layer_slow<64>(actT, lp_col, 1920,  j0, px0, acc);
        writeback(); block_sync_lds();
        mlp_layer_slow<64>(actT, lp_col, 6080,  j0, px0, acc);
        writeback(); block_sync_lds();
        mlp_layer_slow<64>(actT, lp_col, 10240, j0, px0, acc);
        writeback(); block_sync_lds();
        int p = tid;
        float s0 = lp_col[(size_t)14400 << 10];
        float s1 = lp_col[(size_t)14401 << 10];
        float s2 = lp_col[(size_t)14402 << 10];
#pragma unroll 4
        for (int k = 0; k < 64; k++) {
            float a = actT[k * 256 + p];
            s0 = fmaf(a, lp_col[(size_t)(14403 + k * 3 + 0) << 10], s0);
            s1 = fmaf(a, lp_col[(size_t)(14403 + k * 3 + 1) << 10], s1);
            s2 = fmaf(a, lp_col[(size_t)(14403 + k * 3 + 2) << 10], s2);
        }
        int Y = y * 16 + (p >> 4), X = x * 16 + (p & 15);
        size_t base = ((size_t)b * 3) * IMG_H * IMG_W + (size_t)Y * IMG_W + X;
        out[base]                             = tanhf(s0);
        out[base + (size_t)IMG_H * IMG_W]     = tanhf(s1);
        out[base + (size_t)2 * IMG_H * IMG_W] = tanhf(s2);
    }
}

extern "C" void kernel_launch(void* const* d_in, const int* in_sizes, int n_in,
                              void* d_out, int out_size, void* d_ws, size_t ws_size,
                              hipStream_t stream) {
    const float* hr = (const float*)d_in[0];
    const float* lp = (const float*)d_in[1];
    float* out = (float*)d_out;
    float* wsT = (float*)d_ws;

    size_t need = (size_t)BS * 1024 * WROW * sizeof(float);
    if (ws_size >= need) {
        transpose_params<<<BS * 229 * 16, 256, 0, stream>>>(lp, wsT);
        asap_main<true><<<4096, 256, 0, stream>>>(hr, lp, wsT, out);
    } else {
        asap_main<false><<<4096, 256, 0, stream>>>(hr, lp, wsT, out);
    }
}